// Round 2
// baseline (1348.706 us; speedup 1.0000x reference)
//
#include <hip/hip_runtime.h>
#include <stdint.h>

typedef __bf16 bf16;
typedef __bf16 bf16x8 __attribute__((ext_vector_type(8)));
typedef __bf16 bf16x4 __attribute__((ext_vector_type(4)));
typedef float  f32x4  __attribute__((ext_vector_type(4)));

__device__ __forceinline__ void async_load16(const void* g, void* l) {
    __builtin_amdgcn_global_load_lds(
        (const __attribute__((address_space(1))) void*)g,
        (__attribute__((address_space(3))) void*)l,
        16, 0, 0);
}

// ---------------- cast fp32 -> bf16, 8 elems/thread ----------------
__global__ __launch_bounds__(256) void cast_f32_bf16(
        const float* __restrict__ s, bf16* __restrict__ d, int n) {
    int i = (blockIdx.x * 256 + threadIdx.x) * 8;
    if (i >= n) return;
    f32x4 v0 = *(const f32x4*)(s + i);
    f32x4 v1 = *(const f32x4*)(s + i + 4);
    bf16x8 o;
    o[0] = (bf16)v0[0]; o[1] = (bf16)v0[1]; o[2] = (bf16)v0[2]; o[3] = (bf16)v0[3];
    o[4] = (bf16)v1[0]; o[5] = (bf16)v1[1]; o[6] = (bf16)v1[2]; o[7] = (bf16)v1[3];
    *(bf16x8*)(d + i) = o;
}

// ---------------- diagnostic fill (ws too small) ----------------
__global__ __launch_bounds__(256) void fill_f32(float* p, float v, int n) {
    int i = blockIdx.x * 256 + threadIdx.x;
    if (i < n) p[i] = v;
}

// ---------------- GEMM (m97 structure) for the small-N layers ----------------
// C[M,N] = A[M,K] * B[N,K]^T (+bias, relu). 128x128 tile, 4 waves 2x2, BK=32.
// Kept for h1/h2 (N=1024): 512 blocks keeps all CUs busy where 256^2 would not.
template<int RELU, int WF32, int WBF16>
__global__ __launch_bounds__(256, 3) void gemm_bt(
        const bf16* __restrict__ A, int lda,
        const bf16* __restrict__ B, int ldb,
        const float* __restrict__ bias,
        float* __restrict__ Cf, int ldcf,
        bf16* __restrict__ Cb, int ldcb,
        int M, int N, int K) {
    (void)M; (void)N;
    __shared__ __attribute__((aligned(16))) bf16 lA[128 * 32];
    __shared__ __attribute__((aligned(16))) bf16 lB[128 * 32];

    const int t = threadIdx.x;
    const int w = t >> 6, lane = t & 63;
    const int wm = w >> 1, wn = w & 1;
    const int m0 = blockIdx.y * 128, n0 = blockIdx.x * 128;
    const int lane15 = lane & 15, quad = lane >> 4;

    f32x4 acc[4][4] = {};

    const int srow = lane >> 2;
    const int scol = (lane & 3) * 8;
    const int c0 = 2 * w, c1 = 2 * w + 1;
    const bf16* gA0 = A + (size_t)(m0 + c0 * 16 + srow) * lda + scol;
    const bf16* gA1 = A + (size_t)(m0 + c1 * 16 + srow) * lda + scol;
    const bf16* gB0 = B + (size_t)(n0 + c0 * 16 + srow) * ldb + scol;
    const bf16* gB1 = B + (size_t)(n0 + c1 * 16 + srow) * ldb + scol;
    bf16* lA0 = &lA[c0 * 512];
    bf16* lA1 = &lA[c1 * 512];
    bf16* lB0 = &lB[c0 * 512];
    bf16* lB1 = &lB[c1 * 512];

    const bf16* fA = &lA[(wm * 64 + lane15) * 32 + quad * 8];
    const bf16* fB = &lB[(wn * 64 + lane15) * 32 + quad * 8];

    for (int k0 = 0; k0 < K; k0 += 32) {
        async_load16(gA0, lA0);
        async_load16(gA1, lA1);
        async_load16(gB0, lB0);
        async_load16(gB1, lB1);
        gA0 += 32; gA1 += 32; gB0 += 32; gB1 += 32;
        __syncthreads();
        bf16x8 a[4], b[4];
#pragma unroll
        for (int i = 0; i < 4; i++) a[i] = *(const bf16x8*)(fA + i * 16 * 32);
#pragma unroll
        for (int j = 0; j < 4; j++) b[j] = *(const bf16x8*)(fB + j * 16 * 32);
#pragma unroll
        for (int i = 0; i < 4; i++)
#pragma unroll
            for (int j = 0; j < 4; j++)
                acc[i][j] = __builtin_amdgcn_mfma_f32_16x16x32_bf16(a[i], b[j], acc[i][j], 0, 0, 0);
        __syncthreads();
    }

#pragma unroll
    for (int i = 0; i < 4; i++) {
        int row = m0 + wm * 64 + i * 16 + quad * 4;
#pragma unroll
        for (int j = 0; j < 4; j++) {
            int col = n0 + wn * 64 + j * 16 + lane15;
            float bv = bias ? bias[col] : 0.0f;
#pragma unroll
            for (int r = 0; r < 4; r++) {
                float v = acc[i][j][r] + bv;
                if (RELU) v = v > 0.0f ? v : 0.0f;
                if (WF32)  Cf[(size_t)(row + r) * ldcf + col] = v;
                if (WBF16) Cb[(size_t)(row + r) * ldcb + col] = (bf16)v;
            }
        }
    }
}

// ---------------- GEMM 256x256, 4-phase schedule, COUNTED vmcnt (T2+T3+T4+T5) ----
// C[M,N] = A[M,K] * B[N,K]^T (+bias). BM=BN=256, BK=64, 512 threads = 8 waves
// (2M x 4N), each wave owns a 128x64 output tile = acc[8][4] 16x16 frags.
// LDS 128 KiB double-buffered; linear dest for global_load_lds, T2 bank-swizzle
// baked into the STAGING global address (chunk ^ row&7 involution) + read addr.
// Staging of tile T+1 is split into 8 single-load rounds (64 rows each) spread
// over the 4 phases, ordered by consumption:
//   ph0: B rnds 0,1 | ph1: B rnds 2,3 | ph2: A rnds 0,2 | ph3: A rnds 1,3
// (A rnds 0,2 = rows read by Mq=0 phases of wm=0/1; rnds 1,3 by Mq=1.)
// Counted waits, never 0 in steady state (T4, m218: counted-vs-drain0 +38-73%):
//   end-ph1: vmcnt(4)  -> A1',A3' (issued prev ph3) landed; 4 B'' stay in flight
//   end-ph3: vmcnt(2)  -> all B' + A0',A2' landed; A1',A3' stay in flight
// Each wave waits on its own loads; the phase barrier makes it collective.
template<int RELU, int WF32, int WBF16>
__global__ __launch_bounds__(512, 2) void gemm256(
        const bf16* __restrict__ A, int lda,
        const bf16* __restrict__ B, int ldb,
        const float* __restrict__ bias,
        float* __restrict__ Cf, int ldcf,
        bf16* __restrict__ Cb, int ldcb,
        int K) {
    __shared__ __attribute__((aligned(128))) char sm[131072];

    const int t = threadIdx.x;
    const int w = t >> 6;
    const int lane = t & 63;
    const int wm = w >> 2, wn = w & 3;
    const int l15 = lane & 15, quad = lane >> 4;

    // XCD-bijective swizzle (all grids here have nwg % 8 == 0)
    const int gx = gridDim.x;
    const int nwg = gx * gridDim.y;
    const int orig = blockIdx.y * gx + blockIdx.x;
    const int cpx = nwg >> 3;
    const int wg = (orig & 7) * cpx + (orig >> 3);
    const int m0 = (wg / gx) << 8;
    const int n0 = (wg % gx) << 8;

    f32x4 acc[8][4] = {};

    // ---- staging: thread t, round c covers tile row c*64 + t/8 ----
    // source 16B chunk pre-swizzled: chunk = (t&7) ^ (row&7)  [involution]
    const int srow = t >> 3;                       // 0..63
    const int scol = ((t & 7) ^ (srow & 7)) << 3;  // bf16 elements
    const bf16* gA = A + (size_t)(m0 + srow) * lda + scol;
    const bf16* gB = B + (size_t)(n0 + srow) * ldb + scol;
    char* smA = sm + w * 1024;              // wave-uniform base + lane*16
    char* smB = sm + 65536 + w * 1024;
    const size_t rstepA = (size_t)lda << 6;  // 64 rows
    const size_t rstepB = (size_t)ldb << 6;

    // ---- fragment read bases: row = <frag row> + l15, chunk = (ks*4+quad)^(row&7)
    // row&7 == l15&7 for all frags (offsets are multiples of 16 rows).
    // ks=1 is chunk XOR 4 -> byte XOR 64 (no carries: low 11 bits < 2048).
    const int swz = (quad ^ (l15 & 7)) << 4;
    const char* aRd0 = sm + ((wm * 128 + l15) << 7) + swz;
    const char* bRd0 = sm + 65536 + ((wn * 64 + l15) << 7) + swz;
    const char* aRd1 = (const char*)((uintptr_t)aRd0 ^ 64);
    const char* bRd1 = (const char*)((uintptr_t)bRd0 ^ 64);

    bf16x8 a[4][2], b[4][2];
    unsigned boff = 0;

#define STG_A(c, nb) async_load16(gA + (c) * rstepA, smA + (nb) + (c) * 8192)
#define STG_B(c, nb) async_load16(gB + (c) * rstepB, smB + (nb) + (c) * 8192)
#define RD_A(Mq) do { _Pragma("unroll") \
    for (int i = 0; i < 4; i++) { \
        a[i][0] = *(const bf16x8*)(aRd0 + boff + (Mq) * 8192 + i * 2048); \
        a[i][1] = *(const bf16x8*)(aRd1 + boff + (Mq) * 8192 + i * 2048); } } while (0)
#define RD_B(Nq) do { _Pragma("unroll") \
    for (int j = 0; j < 2; j++) { \
        b[(Nq) * 2 + j][0] = *(const bf16x8*)(bRd0 + boff + ((Nq) * 2 + j) * 2048); \
        b[(Nq) * 2 + j][1] = *(const bf16x8*)(bRd1 + boff + ((Nq) * 2 + j) * 2048); } } while (0)
#define MMA(Mq, Nq) do { _Pragma("unroll") \
    for (int i = 0; i < 4; i++) { _Pragma("unroll") \
        for (int j = 0; j < 2; j++) { \
            acc[(Mq) * 4 + i][(Nq) * 2 + j] = __builtin_amdgcn_mfma_f32_16x16x32_bf16( \
                a[i][0], b[(Nq) * 2 + j][0], acc[(Mq) * 4 + i][(Nq) * 2 + j], 0, 0, 0); \
            acc[(Mq) * 4 + i][(Nq) * 2 + j] = __builtin_amdgcn_mfma_f32_16x16x32_bf16( \
                a[i][1], b[(Nq) * 2 + j][1], acc[(Mq) * 4 + i][(Nq) * 2 + j], 0, 0, 0); } } } while (0)
#define BAR() __builtin_amdgcn_s_barrier()
#define WAITLGKM() do { \
    asm volatile("s_waitcnt lgkmcnt(0)" ::: "memory"); \
    __builtin_amdgcn_sched_barrier(0); } while (0)
#define WAITVM(N) do { \
    asm volatile("s_waitcnt vmcnt(" #N ")" ::: "memory"); \
    __builtin_amdgcn_sched_barrier(0); } while (0)

    // prologue: stage tile 0 into buf 0 (full drain once)
    STG_B(0, 0); STG_B(1, 0); STG_B(2, 0); STG_B(3, 0);
    STG_A(0, 0); STG_A(2, 0); STG_A(1, 0); STG_A(3, 0);
    gA += 64; gB += 64;
    WAITVM(0);
    BAR();

    const int nt = K >> 6;
#define KTILE(PF) do { \
    const unsigned nboff = boff ^ 32768u; \
    /* phase 0: Q(0,0) */ \
    RD_A(0); RD_B(0); \
    if (PF) { STG_B(0, nboff); STG_B(1, nboff); } \
    BAR(); WAITLGKM(); \
    __builtin_amdgcn_s_setprio(1); MMA(0, 0); __builtin_amdgcn_s_setprio(0); \
    BAR(); \
    /* phase 1: Q(0,1) */ \
    RD_B(1); \
    if (PF) { STG_B(2, nboff); STG_B(3, nboff); } \
    BAR(); WAITLGKM(); \
    __builtin_amdgcn_s_setprio(1); MMA(0, 1); __builtin_amdgcn_s_setprio(0); \
    if (PF) { WAITVM(4); } else { WAITVM(0); } \
    BAR(); \
    /* phase 2: Q(1,0) */ \
    RD_A(1); \
    if (PF) { STG_A(0, nboff); STG_A(2, nboff); } \
    BAR(); WAITLGKM(); \
    __builtin_amdgcn_s_setprio(1); MMA(1, 0); __builtin_amdgcn_s_setprio(0); \
    BAR(); \
    /* phase 3: Q(1,1) */ \
    if (PF) { STG_A(1, nboff); STG_A(3, nboff); } \
    BAR(); WAITLGKM(); \
    __builtin_amdgcn_s_setprio(1); MMA(1, 1); __builtin_amdgcn_s_setprio(0); \
    if (PF) { WAITVM(2); gA += 64; gB += 64; } \
    BAR(); \
    boff = nboff; \
} while (0)

    for (int T = 0; T < nt - 1; ++T) KTILE(1);
    KTILE(0);
#undef KTILE
#undef STG_A
#undef STG_B
#undef RD_A
#undef RD_B
#undef MMA
#undef BAR
#undef WAITLGKM
#undef WAITVM

    // epilogue: D[row=quad*4+r][col=l15] per 16x16 frag
#pragma unroll
    for (int i = 0; i < 8; i++) {
        int row = m0 + wm * 128 + i * 16 + quad * 4;
#pragma unroll
        for (int j = 0; j < 4; j++) {
            int col = n0 + wn * 64 + j * 16 + l15;
            float bv = bias ? bias[col] : 0.0f;
#pragma unroll
            for (int r = 0; r < 4; r++) {
                float v = acc[i][j][r] + bv;
                if (RELU) v = v > 0.0f ? v : 0.0f;
                if (WF32)  Cf[(size_t)(row + r) * ldcf + col] = v;
                if (WBF16) Cb[(size_t)(row + r) * ldcb + col] = (bf16)v;
            }
        }
    }
}

// ---------------- elementwise combine -> p_pre, q_pre (bf16) ----------------
__global__ __launch_bounds__(256) void combine_pq(
        const bf16* __restrict__ uwb,          // 8192 x 4096 bf16 (u | w)
        const bf16* __restrict__ GBu, const bf16* __restrict__ GBw,
        const float* __restrict__ bias_p, const float* __restrict__ bias_q,
        bf16* __restrict__ pp, bf16* __restrict__ qp) {
    int idx = (blockIdx.x * 256 + threadIdx.x) * 4;   // into 8192x2048
    int row = idx >> 11;
    int col = idx & 2047;
    size_t base = (size_t)row * 4096 + col;
    bf16x4 u4  = *(const bf16x4*)(uwb + base);
    bf16x4 w4  = *(const bf16x4*)(uwb + base + 2048);
    bf16x4 gu4 = *(const bf16x4*)(GBu + base);
    bf16x4 bu4 = *(const bf16x4*)(GBu + base + 2048);
    bf16x4 gw4 = *(const bf16x4*)(GBw + base);
    bf16x4 bw4 = *(const bf16x4*)(GBw + base + 2048);
    bf16x4 po, qo;
#pragma unroll
    for (int r = 0; r < 4; r++) {
        float u = (float)u4[r], w = (float)w4[r];
        float gu = (float)gu4[r], gw = (float)gw4[r];
        float bu = (float)bu4[r], bw = (float)bw4[r];
        float p = u * gu + w * gw + w * bu - u * bw + bias_p[col + r];
        float q = w * gu - u * gw - u * bu - w * bw + bias_q[col + r];
        po[r] = (bf16)p;
        qo[r] = (bf16)q;
    }
    *(bf16x4*)(pp + idx) = po;
    *(bf16x4*)(qp + idx) = qo;
}

extern "C" void kernel_launch(void* const* d_in, const int* in_sizes, int n_in,
                              void* d_out, int out_size, void* d_ws, size_t ws_size,
                              hipStream_t stream) {
    (void)in_sizes; (void)n_in;
    const int BT = 8192, NX = 4096, NR = 1024, NB = 2048;

    const float* x      = (const float*)d_in[0];
    const float* W_h    = (const float*)d_in[1];
    const float* b_h    = (const float*)d_in[2];
    const float* W_h2   = (const float*)d_in[3];
    const float* b_h2   = (const float*)d_in[4];
    const float* W_y    = (const float*)d_in[5];
    const float* b_y    = (const float*)d_in[6];
    const float* G      = (const float*)d_in[7];
    const float* Bm     = (const float*)d_in[8];
    const float* bias_p = (const float*)d_in[9];
    const float* bias_q = (const float*)d_in[10];
    const float* W_p    = (const float*)d_in[11];
    const float* b_p    = (const float*)d_in[12];
    const float* W_q    = (const float*)d_in[13];
    const float* b_q    = (const float*)d_in[14];
    float* out = (float*)d_out;

    // ---- workspace layout (bytes), lifetime-based aliasing ----
    const size_t NEED = 320864256ull;  // ~321 MB
    if (ws_size < NEED) {  // diagnostic: report available MB via d_out
        fill_f32<<<dim3((out_size + 255) / 256), dim3(256), 0, stream>>>(
            out, (float)(ws_size >> 20), out_size);
        return;
    }
    char* ws = (char*)d_ws;
    bf16* xb   = (bf16*)(ws + 0);            // 67.1 MB, dead after h1 GEMM
    bf16* GBu  = (bf16*)(ws + 0);            // 67.1 MB (overlays xb)
    bf16* uwb  = (bf16*)(ws + 67108864);     // 67.1 MB, live through combine
    bf16* GBw  = (bf16*)(ws + 134217728);    // 67.1 MB
    bf16* h1   = (bf16*)(ws + 201326592);    // 16.8 MB, dead after h2 GEMM
    bf16* pp   = (bf16*)(ws + 201326592);    // 33.6 MB (overlays h1+h2, both dead)
    bf16* h2   = (bf16*)(ws + 218103808);    // 16.8 MB, dead after uw GEMM
    bf16* qp   = (bf16*)(ws + 234881024);    // 33.6 MB
    bf16* whb  = (bf16*)(ws + 268435456);    // 8.4 MB
    bf16* wh2b = (bf16*)(ws + 276824064);    // 2.1 MB
    bf16* wyb  = (bf16*)(ws + 278921216);    // 8.4 MB
    bf16* gbm  = (bf16*)(ws + 287309824);    // 16.8 MB: [G; Bm] stacked (4096 x 2048)
    bf16* wpb  = (bf16*)(ws + 304087040);    // 8.4 MB
    bf16* wqb  = (bf16*)(ws + 312475648);    // 8.4 MB

    dim3 blk(256);
    auto cast = [&](const float* s, bf16* d, int n) {
        cast_f32_bf16<<<dim3((n / 8 + 255) / 256), blk, 0, stream>>>(s, d, n);
    };
    cast(x,    xb,   BT * NX);
    cast(W_h,  whb,  NR * NX);
    cast(W_h2, wh2b, NR * NR);
    cast(W_y,  wyb,  NX * NR);
    cast(G,    gbm,            NB * NB);   // rows 0..2047 of stacked weight
    cast(Bm,   gbm + (size_t)NB * NB, NB * NB);   // rows 2048..4095
    cast(W_p,  wpb,  NB * NB);
    cast(W_q,  wqb,  NB * NB);

    // h1 = relu(x @ W_h^T + b_h)            [8192,1024,K=4096] (N=1024 -> 128^2 kernel)
    gemm_bt<1, 0, 1><<<dim3(NR / 128, BT / 128), blk, 0, stream>>>(
        xb, NX, whb, NX, b_h, nullptr, 0, h1, NR, BT, NR, NX);
    // h2 = relu(h1 @ W_h2^T + b_h2)         [8192,1024,K=1024]
    gemm_bt<1, 0, 1><<<dim3(NR / 128, BT / 128), blk, 0, stream>>>(
        h1, NR, wh2b, NR, b_h2, nullptr, 0, h2, NR, BT, NR, NR);

    // ---- big GEMMs on the 256^2 counted-vmcnt kernel ----
    // uw = h2 @ W_y^T + b_y                 [8192,4096,K=1024] -> fp32 d_out + bf16 ws
    gemm256<0, 1, 1><<<dim3(NX / 256, BT / 256), dim3(512), 0, stream>>>(
        h2, NR, wyb, NR, b_y, out, NX, uwb, NX, NR);
    // GBu = u @ [G;Bm]^T, GBw = w @ [G;Bm]^T   [8192,4096,K=2048] each
    gemm256<0, 0, 1><<<dim3(NX / 256, BT / 256), dim3(512), 0, stream>>>(
        uwb,      NX, gbm, NB, nullptr, nullptr, 0, GBu, NX, NB);
    gemm256<0, 0, 1><<<dim3(NX / 256, BT / 256), dim3(512), 0, stream>>>(
        uwb + NB, NX, gbm, NB, nullptr, nullptr, 0, GBw, NX, NB);
    // elementwise combine -> p_pre, q_pre (bf16)
    combine_pq<<<dim3(BT * NB / 4 / 256), blk, 0, stream>>>(
        uwb, GBu, GBw, bias_p, bias_q, pp, qp);
    // p = p_pre @ W_p^T + b_p -> d_out[33554432..]
    gemm256<0, 1, 0><<<dim3(NB / 256, BT / 256), dim3(512), 0, stream>>>(
        pp, NB, wpb, NB, b_p, out + (size_t)BT * NX, NB, nullptr, 0, NB);
    // q = q_pre @ W_q^T + b_q -> d_out[50331648..]
    gemm256<0, 1, 0><<<dim3(NB / 256, BT / 256), dim3(512), 0, stream>>>(
        qp, NB, wqb, NB, b_q, out + (size_t)BT * NX + (size_t)BT * NB, NB, nullptr, 0, NB);
}

// Round 3
// 1277.429 us; speedup vs baseline: 1.0558x; 1.0558x over previous
//
#include <hip/hip_runtime.h>
#include <stdint.h>

typedef __bf16 bf16;
typedef __bf16 bf16x8 __attribute__((ext_vector_type(8)));
typedef __bf16 bf16x4 __attribute__((ext_vector_type(4)));
typedef float  f32x4  __attribute__((ext_vector_type(4)));

__device__ __forceinline__ void async_load16(const void* g, void* l) {
    __builtin_amdgcn_global_load_lds(
        (const __attribute__((address_space(1))) void*)g,
        (__attribute__((address_space(3))) void*)l,
        16, 0, 0);
}

// ---------------- cast fp32 -> bf16, 8 elems/thread ----------------
__global__ __launch_bounds__(256) void cast_f32_bf16(
        const float* __restrict__ s, bf16* __restrict__ d, int n) {
    int i = (blockIdx.x * 256 + threadIdx.x) * 8;
    if (i >= n) return;
    f32x4 v0 = *(const f32x4*)(s + i);
    f32x4 v1 = *(const f32x4*)(s + i + 4);
    bf16x8 o;
    o[0] = (bf16)v0[0]; o[1] = (bf16)v0[1]; o[2] = (bf16)v0[2]; o[3] = (bf16)v0[3];
    o[4] = (bf16)v1[0]; o[5] = (bf16)v1[1]; o[6] = (bf16)v1[2]; o[7] = (bf16)v1[3];
    *(bf16x8*)(d + i) = o;
}

// ---------------- diagnostic fill (ws too small) ----------------
__global__ __launch_bounds__(256) void fill_f32(float* p, float v, int n) {
    int i = blockIdx.x * 256 + threadIdx.x;
    if (i < n) p[i] = v;
}

// ---------------- GEMM (m97 structure) for the small-N layers ----------------
// C[M,N] = A[M,K] * B[N,K]^T (+bias, relu). 128x128 tile, 4 waves 2x2, BK=32.
// Kept for h1/h2 (N=1024): 512 blocks keeps all CUs busy where 256^2 would not.
template<int RELU, int WF32, int WBF16>
__global__ __launch_bounds__(256, 3) void gemm_bt(
        const bf16* __restrict__ A, int lda,
        const bf16* __restrict__ B, int ldb,
        const float* __restrict__ bias,
        float* __restrict__ Cf, int ldcf,
        bf16* __restrict__ Cb, int ldcb,
        int M, int N, int K) {
    (void)M; (void)N;
    __shared__ __attribute__((aligned(16))) bf16 lA[128 * 32];
    __shared__ __attribute__((aligned(16))) bf16 lB[128 * 32];

    const int t = threadIdx.x;
    const int w = t >> 6, lane = t & 63;
    const int wm = w >> 1, wn = w & 1;
    const int m0 = blockIdx.y * 128, n0 = blockIdx.x * 128;
    const int lane15 = lane & 15, quad = lane >> 4;

    f32x4 acc[4][4] = {};

    const int srow = lane >> 2;
    const int scol = (lane & 3) * 8;
    const int c0 = 2 * w, c1 = 2 * w + 1;
    const bf16* gA0 = A + (size_t)(m0 + c0 * 16 + srow) * lda + scol;
    const bf16* gA1 = A + (size_t)(m0 + c1 * 16 + srow) * lda + scol;
    const bf16* gB0 = B + (size_t)(n0 + c0 * 16 + srow) * ldb + scol;
    const bf16* gB1 = B + (size_t)(n0 + c1 * 16 + srow) * ldb + scol;
    bf16* lA0 = &lA[c0 * 512];
    bf16* lA1 = &lA[c1 * 512];
    bf16* lB0 = &lB[c0 * 512];
    bf16* lB1 = &lB[c1 * 512];

    const bf16* fA = &lA[(wm * 64 + lane15) * 32 + quad * 8];
    const bf16* fB = &lB[(wn * 64 + lane15) * 32 + quad * 8];

    for (int k0 = 0; k0 < K; k0 += 32) {
        async_load16(gA0, lA0);
        async_load16(gA1, lA1);
        async_load16(gB0, lB0);
        async_load16(gB1, lB1);
        gA0 += 32; gA1 += 32; gB0 += 32; gB1 += 32;
        __syncthreads();
        bf16x8 a[4], b[4];
#pragma unroll
        for (int i = 0; i < 4; i++) a[i] = *(const bf16x8*)(fA + i * 16 * 32);
#pragma unroll
        for (int j = 0; j < 4; j++) b[j] = *(const bf16x8*)(fB + j * 16 * 32);
#pragma unroll
        for (int i = 0; i < 4; i++)
#pragma unroll
            for (int j = 0; j < 4; j++)
                acc[i][j] = __builtin_amdgcn_mfma_f32_16x16x32_bf16(a[i], b[j], acc[i][j], 0, 0, 0);
        __syncthreads();
    }

#pragma unroll
    for (int i = 0; i < 4; i++) {
        int row = m0 + wm * 64 + i * 16 + quad * 4;
#pragma unroll
        for (int j = 0; j < 4; j++) {
            int col = n0 + wn * 64 + j * 16 + lane15;
            float bv = bias ? bias[col] : 0.0f;
#pragma unroll
            for (int r = 0; r < 4; r++) {
                float v = acc[i][j][r] + bv;
                if (RELU) v = v > 0.0f ? v : 0.0f;
                if (WF32)  Cf[(size_t)(row + r) * ldcf + col] = v;
                if (WBF16) Cb[(size_t)(row + r) * ldcb + col] = (bf16)v;
            }
        }
    }
}

// ---------------- GEMM 256x256, free-run half-tile loop (T2+T4) ----------------
// C[M,N] = A[M,K] * B[N,K]^T (+bias). BM=BN=256, BK=64, 512 threads = 8 waves
// (2M x 4N), per-wave output 128x64 = acc[8][4] 16x16 frags.
// LDS 128 KiB double-buffered; linear dest for global_load_lds, bank-swizzle
// baked into the STAGING global address (chunk ^ row&7 involution) + read addr
// (SQ_LDS_BANK_CONFLICT = 0 measured).
// Schedule: TWO barriers per K-tile (one per half), NO lgkmcnt pinning, NO
// pre-MFMA sched_barrier — the compiler interleaves 32 MFMA + 12-16 ds_read +
// 4 global_load_lds per section with fine-grained lgkmcnt (m97-asm behavior;
// m141: heavy sched_barrier pinning costs 1.7x). One sched_barrier(0) AFTER
// each s_barrier blocks unsafe load-hoisting across the barrier (other waves'
// staging not yet guaranteed landed before the barrier).
// Counted vmcnt, never 0 in steady state (T4):
//   pre-BAR1: vmcnt(4) -> prev-tile A1,A3 remnants landed (this half read them);
//             this tile's 4 B-stages stay in flight.
//   pre-BAR2: vmcnt(2) -> next tile's B' and A0',A2' landed (next first-half
//             reads exactly those); A1',A3' stay in flight.
template<int RELU, int WF32, int WBF16>
__global__ __launch_bounds__(512, 2) void gemm256(
        const bf16* __restrict__ A, int lda,
        const bf16* __restrict__ B, int ldb,
        const float* __restrict__ bias,
        float* __restrict__ Cf, int ldcf,
        bf16* __restrict__ Cb, int ldcb,
        int K) {
    __shared__ __attribute__((aligned(128))) char sm[131072];

    const int t = threadIdx.x;
    const int w = t >> 6;
    const int lane = t & 63;
    const int wm = w >> 2, wn = w & 3;
    const int l15 = lane & 15, quad = lane >> 4;

    // XCD-bijective swizzle (all grids here have nwg % 8 == 0)
    const int gx = gridDim.x;
    const int nwg = gx * gridDim.y;
    const int orig = blockIdx.y * gx + blockIdx.x;
    const int cpx = nwg >> 3;
    const int wg = (orig & 7) * cpx + (orig >> 3);
    const int m0 = (wg / gx) << 8;
    const int n0 = (wg % gx) << 8;

    f32x4 acc[8][4] = {};

    // ---- staging: thread t, round c covers tile row c*64 + t/8 ----
    // source 16B chunk pre-swizzled: chunk = (t&7) ^ (row&7)  [involution]
    const int srow = t >> 3;                       // 0..63
    const int scol = ((t & 7) ^ (srow & 7)) << 3;  // bf16 elements
    const bf16* gA = A + (size_t)(m0 + srow) * lda + scol;
    const bf16* gB = B + (size_t)(n0 + srow) * ldb + scol;
    char* smA = sm + w * 1024;              // wave-uniform base + lane*16
    char* smB = sm + 65536 + w * 1024;
    const size_t rstepA = (size_t)lda << 6;  // 64 rows
    const size_t rstepB = (size_t)ldb << 6;

    // ---- fragment read bases: row = <frag row> + l15, chunk = (ks*4+quad)^(row&7)
    // row&7 == l15&7 for all frags (offsets are multiples of 16 rows).
    // ks=1 is chunk XOR 4 -> byte XOR 64 (no carries: low 11 bits < 2048).
    const int swz = (quad ^ (l15 & 7)) << 4;
    const char* aRd0 = sm + ((wm * 128 + l15) << 7) + swz;
    const char* bRd0 = sm + 65536 + ((wn * 64 + l15) << 7) + swz;
    const char* aRd1 = (const char*)((uintptr_t)aRd0 ^ 64);
    const char* bRd1 = (const char*)((uintptr_t)bRd0 ^ 64);

    bf16x8 a[4][2], b[4][2];
    unsigned boff = 0;

#define STG_A(c, nb) async_load16(gA + (c) * rstepA, smA + (nb) + (c) * 8192)
#define STG_B(c, nb) async_load16(gB + (c) * rstepB, smB + (nb) + (c) * 8192)
#define RD_A(Mq) do { _Pragma("unroll") \
    for (int i = 0; i < 4; i++) { \
        a[i][0] = *(const bf16x8*)(aRd0 + boff + (Mq) * 8192 + i * 2048); \
        a[i][1] = *(const bf16x8*)(aRd1 + boff + (Mq) * 8192 + i * 2048); } } while (0)
#define RD_B(Nq) do { _Pragma("unroll") \
    for (int j = 0; j < 2; j++) { \
        b[(Nq) * 2 + j][0] = *(const bf16x8*)(bRd0 + boff + ((Nq) * 2 + j) * 2048); \
        b[(Nq) * 2 + j][1] = *(const bf16x8*)(bRd1 + boff + ((Nq) * 2 + j) * 2048); } } while (0)
#define MMA(Mq, Nq) do { _Pragma("unroll") \
    for (int i = 0; i < 4; i++) { _Pragma("unroll") \
        for (int j = 0; j < 2; j++) { \
            acc[(Mq) * 4 + i][(Nq) * 2 + j] = __builtin_amdgcn_mfma_f32_16x16x32_bf16( \
                a[i][0], b[(Nq) * 2 + j][0], acc[(Mq) * 4 + i][(Nq) * 2 + j], 0, 0, 0); \
            acc[(Mq) * 4 + i][(Nq) * 2 + j] = __builtin_amdgcn_mfma_f32_16x16x32_bf16( \
                a[i][1], b[(Nq) * 2 + j][1], acc[(Mq) * 4 + i][(Nq) * 2 + j], 0, 0, 0); } } } while (0)
#define BARP() do { __builtin_amdgcn_s_barrier(); \
    __builtin_amdgcn_sched_barrier(0); } while (0)
#define WAITVM(N) do { \
    asm volatile("s_waitcnt vmcnt(" #N ")" ::: "memory"); } while (0)

    // prologue: stage tile 0 into buf 0 (full drain once)
    STG_B(0, 0); STG_B(1, 0); STG_B(2, 0); STG_B(3, 0);
    STG_A(0, 0); STG_A(2, 0); STG_A(1, 0); STG_A(3, 0);
    gA += 64; gB += 64;
    WAITVM(0);
    BARP();

    const int nt = K >> 6;
#define KTILE(PF) do { \
    const unsigned nboff = boff ^ 32768u; \
    /* ---- first half: quadrants (0,0),(0,1); stage next tile's B ---- */ \
    RD_A(0); RD_B(0); RD_B(1); \
    if (PF) { STG_B(0, nboff); STG_B(1, nboff); STG_B(2, nboff); STG_B(3, nboff); } \
    MMA(0, 0); MMA(0, 1); \
    if (PF) { WAITVM(4); } \
    BARP(); \
    /* ---- second half: quadrants (1,0),(1,1); stage next tile's A ---- */ \
    RD_A(1); \
    if (PF) { STG_A(0, nboff); STG_A(2, nboff); STG_A(1, nboff); STG_A(3, nboff); } \
    MMA(1, 0); MMA(1, 1); \
    if (PF) { WAITVM(2); gA += 64; gB += 64; } \
    BARP(); \
    boff = nboff; \
} while (0)

    for (int T = 0; T < nt - 1; ++T) KTILE(1);
    KTILE(0);
#undef KTILE
#undef STG_A
#undef STG_B
#undef RD_A
#undef RD_B
#undef MMA
#undef BARP
#undef WAITVM

    // epilogue: D[row=quad*4+r][col=l15] per 16x16 frag
#pragma unroll
    for (int i = 0; i < 8; i++) {
        int row = m0 + wm * 128 + i * 16 + quad * 4;
#pragma unroll
        for (int j = 0; j < 4; j++) {
            int col = n0 + wn * 64 + j * 16 + l15;
            float bv = bias ? bias[col] : 0.0f;
#pragma unroll
            for (int r = 0; r < 4; r++) {
                float v = acc[i][j][r] + bv;
                if (RELU) v = v > 0.0f ? v : 0.0f;
                if (WF32)  Cf[(size_t)(row + r) * ldcf + col] = v;
                if (WBF16) Cb[(size_t)(row + r) * ldcb + col] = (bf16)v;
            }
        }
    }
}

// ---------------- elementwise combine -> p_pre, q_pre (bf16) ----------------
__global__ __launch_bounds__(256) void combine_pq(
        const bf16* __restrict__ uwb,          // 8192 x 4096 bf16 (u | w)
        const bf16* __restrict__ GBu, const bf16* __restrict__ GBw,
        const float* __restrict__ bias_p, const float* __restrict__ bias_q,
        bf16* __restrict__ pp, bf16* __restrict__ qp) {
    int idx = (blockIdx.x * 256 + threadIdx.x) * 4;   // into 8192x2048
    int row = idx >> 11;
    int col = idx & 2047;
    size_t base = (size_t)row * 4096 + col;
    bf16x4 u4  = *(const bf16x4*)(uwb + base);
    bf16x4 w4  = *(const bf16x4*)(uwb + base + 2048);
    bf16x4 gu4 = *(const bf16x4*)(GBu + base);
    bf16x4 bu4 = *(const bf16x4*)(GBu + base + 2048);
    bf16x4 gw4 = *(const bf16x4*)(GBw + base);
    bf16x4 bw4 = *(const bf16x4*)(GBw + base + 2048);
    bf16x4 po, qo;
#pragma unroll
    for (int r = 0; r < 4; r++) {
        float u = (float)u4[r], w = (float)w4[r];
        float gu = (float)gu4[r], gw = (float)gw4[r];
        float bu = (float)bu4[r], bw = (float)bw4[r];
        float p = u * gu + w * gw + w * bu - u * bw + bias_p[col + r];
        float q = w * gu - u * gw - u * bu - w * bw + bias_q[col + r];
        po[r] = (bf16)p;
        qo[r] = (bf16)q;
    }
    *(bf16x4*)(pp + idx) = po;
    *(bf16x4*)(qp + idx) = qo;
}

extern "C" void kernel_launch(void* const* d_in, const int* in_sizes, int n_in,
                              void* d_out, int out_size, void* d_ws, size_t ws_size,
                              hipStream_t stream) {
    (void)in_sizes; (void)n_in;
    const int BT = 8192, NX = 4096, NR = 1024, NB = 2048;

    const float* x      = (const float*)d_in[0];
    const float* W_h    = (const float*)d_in[1];
    const float* b_h    = (const float*)d_in[2];
    const float* W_h2   = (const float*)d_in[3];
    const float* b_h2   = (const float*)d_in[4];
    const float* W_y    = (const float*)d_in[5];
    const float* b_y    = (const float*)d_in[6];
    const float* G      = (const float*)d_in[7];
    const float* Bm     = (const float*)d_in[8];
    const float* bias_p = (const float*)d_in[9];
    const float* bias_q = (const float*)d_in[10];
    const float* W_p    = (const float*)d_in[11];
    const float* b_p    = (const float*)d_in[12];
    const float* W_q    = (const float*)d_in[13];
    const float* b_q    = (const float*)d_in[14];
    float* out = (float*)d_out;

    // ---- workspace layout (bytes), lifetime-based aliasing ----
    const size_t NEED = 320864256ull;  // ~321 MB
    if (ws_size < NEED) {  // diagnostic: report available MB via d_out
        fill_f32<<<dim3((out_size + 255) / 256), dim3(256), 0, stream>>>(
            out, (float)(ws_size >> 20), out_size);
        return;
    }
    char* ws = (char*)d_ws;
    bf16* xb   = (bf16*)(ws + 0);            // 67.1 MB, dead after h1 GEMM
    bf16* GBu  = (bf16*)(ws + 0);            // 67.1 MB (overlays xb)
    bf16* uwb  = (bf16*)(ws + 67108864);     // 67.1 MB, live through combine
    bf16* GBw  = (bf16*)(ws + 134217728);    // 67.1 MB
    bf16* h1   = (bf16*)(ws + 201326592);    // 16.8 MB, dead after h2 GEMM
    bf16* pp   = (bf16*)(ws + 201326592);    // 33.6 MB (overlays h1+h2, both dead)
    bf16* h2   = (bf16*)(ws + 218103808);    // 16.8 MB, dead after uw GEMM
    bf16* qp   = (bf16*)(ws + 234881024);    // 33.6 MB
    bf16* whb  = (bf16*)(ws + 268435456);    // 8.4 MB
    bf16* wh2b = (bf16*)(ws + 276824064);    // 2.1 MB
    bf16* wyb  = (bf16*)(ws + 278921216);    // 8.4 MB
    bf16* gbm  = (bf16*)(ws + 287309824);    // 16.8 MB: [G; Bm] stacked (4096 x 2048)
    bf16* wpb  = (bf16*)(ws + 304087040);    // 8.4 MB
    bf16* wqb  = (bf16*)(ws + 312475648);    // 8.4 MB

    dim3 blk(256);
    auto cast = [&](const float* s, bf16* d, int n) {
        cast_f32_bf16<<<dim3((n / 8 + 255) / 256), blk, 0, stream>>>(s, d, n);
    };
    cast(x,    xb,   BT * NX);
    cast(W_h,  whb,  NR * NX);
    cast(W_h2, wh2b, NR * NR);
    cast(W_y,  wyb,  NX * NR);
    cast(G,    gbm,            NB * NB);   // rows 0..2047 of stacked weight
    cast(Bm,   gbm + (size_t)NB * NB, NB * NB);   // rows 2048..4095
    cast(W_p,  wpb,  NB * NB);
    cast(W_q,  wqb,  NB * NB);

    // h1 = relu(x @ W_h^T + b_h)            [8192,1024,K=4096] (N=1024 -> 128^2 kernel)
    gemm_bt<1, 0, 1><<<dim3(NR / 128, BT / 128), blk, 0, stream>>>(
        xb, NX, whb, NX, b_h, nullptr, 0, h1, NR, BT, NR, NX);
    // h2 = relu(h1 @ W_h2^T + b_h2)         [8192,1024,K=1024]
    gemm_bt<1, 0, 1><<<dim3(NR / 128, BT / 128), blk, 0, stream>>>(
        h1, NR, wh2b, NR, b_h2, nullptr, 0, h2, NR, BT, NR, NR);

    // ---- big GEMMs on the 256^2 free-run kernel ----
    // uw = h2 @ W_y^T + b_y                 [8192,4096,K=1024] -> fp32 d_out + bf16 ws
    gemm256<0, 1, 1><<<dim3(NX / 256, BT / 256), dim3(512), 0, stream>>>(
        h2, NR, wyb, NR, b_y, out, NX, uwb, NX, NR);
    // GBu = u @ [G;Bm]^T, GBw = w @ [G;Bm]^T   [8192,4096,K=2048] each
    gemm256<0, 0, 1><<<dim3(NX / 256, BT / 256), dim3(512), 0, stream>>>(
        uwb,      NX, gbm, NB, nullptr, nullptr, 0, GBu, NX, NB);
    gemm256<0, 0, 1><<<dim3(NX / 256, BT / 256), dim3(512), 0, stream>>>(
        uwb + NB, NX, gbm, NB, nullptr, nullptr, 0, GBw, NX, NB);
    // elementwise combine -> p_pre, q_pre (bf16)
    combine_pq<<<dim3(BT * NB / 4 / 256), blk, 0, stream>>>(
        uwb, GBu, GBw, bias_p, bias_q, pp, qp);
    // p = p_pre @ W_p^T + b_p -> d_out[33554432..]
    gemm256<0, 1, 0><<<dim3(NB / 256, BT / 256), dim3(512), 0, stream>>>(
        pp, NB, wpb, NB, b_p, out + (size_t)BT * NX, NB, nullptr, 0, NB);
    // q = q_pre @ W_q^T + b_q -> d_out[50331648..]
    gemm256<0, 1, 0><<<dim3(NB / 256, BT / 256), dim3(512), 0, stream>>>(
        qp, NB, wqb, NB, b_q, out + (size_t)BT * NX + (size_t)BT * NB, NB, nullptr, 0, NB);
}

// Round 4
// 1270.588 us; speedup vs baseline: 1.0615x; 1.0054x over previous
//
#include <hip/hip_runtime.h>
#include <stdint.h>

typedef __bf16 bf16;
typedef __bf16 bf16x8 __attribute__((ext_vector_type(8)));
typedef __bf16 bf16x4 __attribute__((ext_vector_type(4)));
typedef float  f32x4  __attribute__((ext_vector_type(4)));

__device__ __forceinline__ void async_load16(const void* g, void* l) {
    __builtin_amdgcn_global_load_lds(
        (const __attribute__((address_space(1))) void*)g,
        (__attribute__((address_space(3))) void*)l,
        16, 0, 0);
}

// ---------------- cast fp32 -> bf16, 8 elems/thread ----------------
__global__ __launch_bounds__(256) void cast_f32_bf16(
        const float* __restrict__ s, bf16* __restrict__ d, int n) {
    int i = (blockIdx.x * 256 + threadIdx.x) * 8;
    if (i >= n) return;
    f32x4 v0 = *(const f32x4*)(s + i);
    f32x4 v1 = *(const f32x4*)(s + i + 4);
    bf16x8 o;
    o[0] = (bf16)v0[0]; o[1] = (bf16)v0[1]; o[2] = (bf16)v0[2]; o[3] = (bf16)v0[3];
    o[4] = (bf16)v1[0]; o[5] = (bf16)v1[1]; o[6] = (bf16)v1[2]; o[7] = (bf16)v1[3];
    *(bf16x8*)(d + i) = o;
}

// ---------------- diagnostic fill (ws too small) ----------------
__global__ __launch_bounds__(256) void fill_f32(float* p, float v, int n) {
    int i = blockIdx.x * 256 + threadIdx.x;
    if (i < n) p[i] = v;
}

// ---------------- GEMM (m97 structure) for the small-N layers ----------------
// C[M,N] = A[M,K] * B[N,K]^T (+bias, relu). 128x128 tile, 4 waves 2x2, BK=32.
template<int RELU, int WF32, int WBF16>
__global__ __launch_bounds__(256, 3) void gemm_bt(
        const bf16* __restrict__ A, int lda,
        const bf16* __restrict__ B, int ldb,
        const float* __restrict__ bias,
        float* __restrict__ Cf, int ldcf,
        bf16* __restrict__ Cb, int ldcb,
        int M, int N, int K) {
    (void)M; (void)N;
    __shared__ __attribute__((aligned(16))) bf16 lA[128 * 32];
    __shared__ __attribute__((aligned(16))) bf16 lB[128 * 32];

    const int t = threadIdx.x;
    const int w = t >> 6, lane = t & 63;
    const int wm = w >> 1, wn = w & 1;
    const int m0 = blockIdx.y * 128, n0 = blockIdx.x * 128;
    const int lane15 = lane & 15, quad = lane >> 4;

    f32x4 acc[4][4] = {};

    const int srow = lane >> 2;
    const int scol = (lane & 3) * 8;
    const int c0 = 2 * w, c1 = 2 * w + 1;
    const bf16* gA0 = A + (size_t)(m0 + c0 * 16 + srow) * lda + scol;
    const bf16* gA1 = A + (size_t)(m0 + c1 * 16 + srow) * lda + scol;
    const bf16* gB0 = B + (size_t)(n0 + c0 * 16 + srow) * ldb + scol;
    const bf16* gB1 = B + (size_t)(n0 + c1 * 16 + srow) * ldb + scol;
    bf16* lA0 = &lA[c0 * 512];
    bf16* lA1 = &lA[c1 * 512];
    bf16* lB0 = &lB[c0 * 512];
    bf16* lB1 = &lB[c1 * 512];

    const bf16* fA = &lA[(wm * 64 + lane15) * 32 + quad * 8];
    const bf16* fB = &lB[(wn * 64 + lane15) * 32 + quad * 8];

    for (int k0 = 0; k0 < K; k0 += 32) {
        async_load16(gA0, lA0);
        async_load16(gA1, lA1);
        async_load16(gB0, lB0);
        async_load16(gB1, lB1);
        gA0 += 32; gA1 += 32; gB0 += 32; gB1 += 32;
        __syncthreads();
        bf16x8 a[4], b[4];
#pragma unroll
        for (int i = 0; i < 4; i++) a[i] = *(const bf16x8*)(fA + i * 16 * 32);
#pragma unroll
        for (int j = 0; j < 4; j++) b[j] = *(const bf16x8*)(fB + j * 16 * 32);
#pragma unroll
        for (int i = 0; i < 4; i++)
#pragma unroll
            for (int j = 0; j < 4; j++)
                acc[i][j] = __builtin_amdgcn_mfma_f32_16x16x32_bf16(a[i], b[j], acc[i][j], 0, 0, 0);
        __syncthreads();
    }

#pragma unroll
    for (int i = 0; i < 4; i++) {
        int row = m0 + wm * 64 + i * 16 + quad * 4;
#pragma unroll
        for (int j = 0; j < 4; j++) {
            int col = n0 + wn * 64 + j * 16 + lane15;
            float bv = bias ? bias[col] : 0.0f;
#pragma unroll
            for (int r = 0; r < 4; r++) {
                float v = acc[i][j][r] + bv;
                if (RELU) v = v > 0.0f ? v : 0.0f;
                if (WF32)  Cf[(size_t)(row + r) * ldcf + col] = v;
                if (WBF16) Cb[(size_t)(row + r) * ldcb + col] = (bf16)v;
            }
        }
    }
}

// ---------------- GEMM 256x256, DEEP-pipelined 4-phase schedule ----------------
// C[M,N] = A[M,K] * B[N,K]^T (+bias). BM=BN=256, BK=64, 512 threads = 8 waves,
// per-wave output: rows {Mq*128 + wm*64 ..+63}, cols {Nq*128 + wn*32 ..+31}.
// Fragment->staging-round mapping is phase-disjoint:
//   phase Mq reads ONLY A rounds {2Mq,2Mq+1}; phase Nq ONLY B rounds {2Nq,2Nq+1}
// which legalizes a 1.5-K-tile-deep FIFO pipeline (the shallow-lead stall was
// the 28%-MfmaUtil bottleneck of rounds 1-3: waits hit loads issued <400cy
// earlier vs ~900cy HBM latency).
// Steady-state per tile T (buf p = T&1; reads reg-cached, one phase per round):
//   ph0: RD A0A1,B0B1 | STG B2B3(T+1)->p^1 | MMA(0,0) | vmcnt(8) | bar
//   ph1: RD B2B3      | STG A2A3(T+1)->p^1 | MMA(0,1) | vmcnt(8) | bar
//   ph2: RD A2A3      | STG A0A1(T+2)->p   | MMA(1,0)
//   ph3:              | STG B0B1(T+2)->p   | MMA(1,1) | vmcnt(8) | bar
// Every wait targets loads issued >=4 phases earlier; 12 loads max in flight.
// Overwrite hazards: each overwrite is >=2 barriers after the round's last read
// (reads are reg-cached to a single phase). Tail: HALF tile (no T+2 stages,
// waits 8/8/4) then LAST (no stages, waits 2/0/0). Prologue stages 6 pairs in
// FIFO order A0A1(0),B0B1(0),B2B3(0),A2A3(0),A0A1(1),B0B1(1) then vmcnt(8).
template<int RELU, int WF32, int WBF16>
__global__ __launch_bounds__(512, 2) void gemm256(
        const bf16* __restrict__ A, int lda,
        const bf16* __restrict__ B, int ldb,
        const float* __restrict__ bias,
        float* __restrict__ Cf, int ldcf,
        bf16* __restrict__ Cb, int ldcb,
        int K) {
    __shared__ __attribute__((aligned(128))) char sm[131072];

    const int t = threadIdx.x;
    const int w = t >> 6;
    const int lane = t & 63;
    const int wm = w >> 2, wn = w & 3;
    const int l15 = lane & 15, quad = lane >> 4;

    // XCD-bijective swizzle (all grids here have nwg % 8 == 0)
    const int gx = gridDim.x;
    const int nwg = gx * gridDim.y;
    const int orig = blockIdx.y * gx + blockIdx.x;
    const int cpx = nwg >> 3;
    const int wg = (orig & 7) * cpx + (orig >> 3);
    const int m0 = (wg / gx) << 8;
    const int n0 = (wg % gx) << 8;

    f32x4 acc[8][4] = {};

    // ---- staging: thread t covers tile row c*64 + t/8 of round c ----
    // source 16B chunk pre-swizzled: chunk = (t&7) ^ (row&7)  [involution]
    const int srow = t >> 3;                       // 0..63
    const int scol = ((t & 7) ^ (srow & 7)) << 3;  // bf16 elements
    const bf16* gA = A + (size_t)(m0 + srow) * lda + scol;
    const bf16* gB = B + (size_t)(n0 + srow) * ldb + scol;
    char* smA = sm + w * 1024;              // wave-uniform base + lane*16
    char* smB = sm + 65536 + w * 1024;
    const size_t rstepA = (size_t)lda << 6;  // 64 rows
    const size_t rstepB = (size_t)ldb << 6;

    // ---- fragment read bases (phase-disjoint round mapping) ----
    // A: row = Mq*128 + wm*64 + i*16 + l15 -> byte Mq*16384 + wm*8192 + i*2048 + l15*128
    // B: row = Nq*128 + wn*32 + j*16 + l15 -> byte Nq*16384 + (wn>>1)*8192
    //                                         + ((wn&1)*32 + j*16 + l15)*128
    // chunk swizzle: phys chunk = (ks*4+quad) ^ (row&7); row&7 == l15&7 always.
    // ks=1 flips byte bit 6 (chunk^4) -> pointer ^64, carry-free.
    const int swz = (quad ^ (l15 & 7)) << 4;
    const char* aRd0 = sm + (wm << 13) + (l15 << 7) + swz;
    const char* bRd0 = sm + 65536 + ((wn >> 1) << 13) + ((((wn & 1) << 5) + l15) << 7) + swz;
    const char* aRd1 = (const char*)((uintptr_t)aRd0 ^ 64);
    const char* bRd1 = (const char*)((uintptr_t)bRd0 ^ 64);

    bf16x8 a[4][2], b[4][2];
    unsigned boff = 0;

#define STG_A(c, ko, nb) async_load16(gA + (ko) + (c) * rstepA, smA + (nb) + (c) * 8192)
#define STG_B(c, ko, nb) async_load16(gB + (ko) + (c) * rstepB, smB + (nb) + (c) * 8192)
#define RD_A(Mq) do { _Pragma("unroll") \
    for (int i = 0; i < 4; i++) { \
        a[i][0] = *(const bf16x8*)(aRd0 + boff + (Mq) * 16384 + i * 2048); \
        a[i][1] = *(const bf16x8*)(aRd1 + boff + (Mq) * 16384 + i * 2048); } } while (0)
#define RD_B(Nq) do { _Pragma("unroll") \
    for (int j = 0; j < 2; j++) { \
        b[(Nq) * 2 + j][0] = *(const bf16x8*)(bRd0 + boff + (Nq) * 16384 + j * 2048); \
        b[(Nq) * 2 + j][1] = *(const bf16x8*)(bRd1 + boff + (Nq) * 16384 + j * 2048); } } while (0)
#define MMA(Mq, Nq) do { __builtin_amdgcn_s_setprio(1); _Pragma("unroll") \
    for (int i = 0; i < 4; i++) { _Pragma("unroll") \
        for (int j = 0; j < 2; j++) { \
            acc[(Mq) * 4 + i][(Nq) * 2 + j] = __builtin_amdgcn_mfma_f32_16x16x32_bf16( \
                a[i][0], b[(Nq) * 2 + j][0], acc[(Mq) * 4 + i][(Nq) * 2 + j], 0, 0, 0); \
            acc[(Mq) * 4 + i][(Nq) * 2 + j] = __builtin_amdgcn_mfma_f32_16x16x32_bf16( \
                a[i][1], b[(Nq) * 2 + j][1], acc[(Mq) * 4 + i][(Nq) * 2 + j], 0, 0, 0); } } \
    __builtin_amdgcn_s_setprio(0); } while (0)
#define BARP() do { __builtin_amdgcn_s_barrier(); \
    __builtin_amdgcn_sched_barrier(0); } while (0)
#define WAITVM_IMPL(N) asm volatile("s_waitcnt vmcnt(" #N ")" ::: "memory")
#define WAITVM(N) WAITVM_IMPL(N)

    // prologue: FIFO order A0A1(0),B0B1(0),B2B3(0),A2A3(0),A0A1(1),B0B1(1)
    STG_A(0, 0, 0); STG_A(1, 0, 0); STG_B(0, 0, 0); STG_B(1, 0, 0);
    STG_B(2, 0, 0); STG_B(3, 0, 0); STG_A(2, 0, 0); STG_A(3, 0, 0);
    STG_A(0, 64, 32768); STG_A(1, 64, 32768); STG_B(0, 64, 32768); STG_B(1, 64, 32768);
    gA += 64; gB += 64;   // now points at k=(T+1)*64 for T=0
    WAITVM(8);            // A0A1(0),B0B1(0) landed; 8 stay in flight
    BARP();

    const int nt = K >> 6;
#define KTILE(SG1, SG2, W0, W1, W3) do { \
    const unsigned nboff = boff ^ 32768u; \
    /* ph0: Q(0,0); stage B2B3(T+1) */ \
    RD_A(0); RD_B(0); \
    if (SG1) { STG_B(2, 0, nboff); STG_B(3, 0, nboff); } \
    MMA(0, 0); \
    WAITVM(W0); BARP(); \
    /* ph1: Q(0,1); stage A2A3(T+1) */ \
    RD_B(1); \
    if (SG1) { STG_A(2, 0, nboff); STG_A(3, 0, nboff); } \
    MMA(0, 1); \
    WAITVM(W1); BARP(); \
    /* ph2+3: Q(1,0),Q(1,1); stage A0A1(T+2), B0B1(T+2) */ \
    RD_A(1); \
    if (SG2) { STG_A(0, 64, boff); STG_A(1, 64, boff); } \
    MMA(1, 0); \
    if (SG2) { STG_B(0, 64, boff); STG_B(1, 64, boff); } \
    MMA(1, 1); \
    WAITVM(W3); BARP(); \
    boff = nboff; \
} while (0)

    for (int T = 0; T < nt - 2; ++T) {
        KTILE(1, 1, 8, 8, 8);
        gA += 64; gB += 64;
    }
    KTILE(1, 0, 8, 8, 4);   // tile nt-2: no T+2 stages
    KTILE(0, 0, 2, 0, 0);   // tile nt-1: no stages, drain
#undef KTILE
#undef STG_A
#undef STG_B
#undef RD_A
#undef RD_B
#undef MMA
#undef BARP
#undef WAITVM
#undef WAITVM_IMPL

    // epilogue: acc[i][j] -> row Mq*128+wm*64+(i&3)*16+quad*4, col Nq*128+wn*32+(j&1)*16+l15
#pragma unroll
    for (int i = 0; i < 8; i++) {
        int row = m0 + ((i >> 2) << 7) + (wm << 6) + ((i & 3) << 4) + (quad << 2);
#pragma unroll
        for (int j = 0; j < 4; j++) {
            int col = n0 + ((j >> 1) << 7) + (wn << 5) + ((j & 1) << 4) + l15;
            float bv = bias ? bias[col] : 0.0f;
#pragma unroll
            for (int r = 0; r < 4; r++) {
                float v = acc[i][j][r] + bv;
                if (RELU) v = v > 0.0f ? v : 0.0f;
                if (WF32)  Cf[(size_t)(row + r) * ldcf + col] = v;
                if (WBF16) Cb[(size_t)(row + r) * ldcb + col] = (bf16)v;
            }
        }
    }
}

// ---------------- elementwise combine -> p_pre, q_pre (bf16) ----------------
__global__ __launch_bounds__(256) void combine_pq(
        const bf16* __restrict__ uwb,          // 8192 x 4096 bf16 (u | w)
        const bf16* __restrict__ GBu, const bf16* __restrict__ GBw,
        const float* __restrict__ bias_p, const float* __restrict__ bias_q,
        bf16* __restrict__ pp, bf16* __restrict__ qp) {
    int idx = (blockIdx.x * 256 + threadIdx.x) * 4;   // into 8192x2048
    int row = idx >> 11;
    int col = idx & 2047;
    size_t base = (size_t)row * 4096 + col;
    bf16x4 u4  = *(const bf16x4*)(uwb + base);
    bf16x4 w4  = *(const bf16x4*)(uwb + base + 2048);
    bf16x4 gu4 = *(const bf16x4*)(GBu + base);
    bf16x4 bu4 = *(const bf16x4*)(GBu + base + 2048);
    bf16x4 gw4 = *(const bf16x4*)(GBw + base);
    bf16x4 bw4 = *(const bf16x4*)(GBw + base + 2048);
    bf16x4 po, qo;
#pragma unroll
    for (int r = 0; r < 4; r++) {
        float u = (float)u4[r], w = (float)w4[r];
        float gu = (float)gu4[r], gw = (float)gw4[r];
        float bu = (float)bu4[r], bw = (float)bw4[r];
        float p = u * gu + w * gw + w * bu - u * bw + bias_p[col + r];
        float q = w * gu - u * gw - u * bu - w * bw + bias_q[col + r];
        po[r] = (bf16)p;
        qo[r] = (bf16)q;
    }
    *(bf16x4*)(pp + idx) = po;
    *(bf16x4*)(qp + idx) = qo;
}

extern "C" void kernel_launch(void* const* d_in, const int* in_sizes, int n_in,
                              void* d_out, int out_size, void* d_ws, size_t ws_size,
                              hipStream_t stream) {
    (void)in_sizes; (void)n_in;
    const int BT = 8192, NX = 4096, NR = 1024, NB = 2048;

    const float* x      = (const float*)d_in[0];
    const float* W_h    = (const float*)d_in[1];
    const float* b_h    = (const float*)d_in[2];
    const float* W_h2   = (const float*)d_in[3];
    const float* b_h2   = (const float*)d_in[4];
    const float* W_y    = (const float*)d_in[5];
    const float* b_y    = (const float*)d_in[6];
    const float* G      = (const float*)d_in[7];
    const float* Bm     = (const float*)d_in[8];
    const float* bias_p = (const float*)d_in[9];
    const float* bias_q = (const float*)d_in[10];
    const float* W_p    = (const float*)d_in[11];
    const float* b_p    = (const float*)d_in[12];
    const float* W_q    = (const float*)d_in[13];
    const float* b_q    = (const float*)d_in[14];
    float* out = (float*)d_out;

    // ---- workspace layout (bytes), lifetime-based aliasing ----
    const size_t NEED = 320864256ull;  // ~321 MB
    if (ws_size < NEED) {  // diagnostic: report available MB via d_out
        fill_f32<<<dim3((out_size + 255) / 256), dim3(256), 0, stream>>>(
            out, (float)(ws_size >> 20), out_size);
        return;
    }
    char* ws = (char*)d_ws;
    bf16* xb   = (bf16*)(ws + 0);            // 67.1 MB, dead after h1 GEMM
    bf16* GBu  = (bf16*)(ws + 0);            // 67.1 MB (overlays xb)
    bf16* uwb  = (bf16*)(ws + 67108864);     // 67.1 MB, live through combine
    bf16* GBw  = (bf16*)(ws + 134217728);    // 67.1 MB
    bf16* h1   = (bf16*)(ws + 201326592);    // 16.8 MB, dead after h2 GEMM
    bf16* pp   = (bf16*)(ws + 201326592);    // 33.6 MB (overlays h1+h2, both dead)
    bf16* h2   = (bf16*)(ws + 218103808);    // 16.8 MB, dead after uw GEMM
    bf16* qp   = (bf16*)(ws + 234881024);    // 33.6 MB
    bf16* whb  = (bf16*)(ws + 268435456);    // 8.4 MB
    bf16* wh2b = (bf16*)(ws + 276824064);    // 2.1 MB
    bf16* wyb  = (bf16*)(ws + 278921216);    // 8.4 MB
    bf16* gbm  = (bf16*)(ws + 287309824);    // 16.8 MB: [G; Bm] stacked (4096 x 2048)
    bf16* wpb  = (bf16*)(ws + 304087040);    // 8.4 MB
    bf16* wqb  = (bf16*)(ws + 312475648);    // 8.4 MB

    dim3 blk(256);
    auto cast = [&](const float* s, bf16* d, int n) {
        cast_f32_bf16<<<dim3((n / 8 + 255) / 256), blk, 0, stream>>>(s, d, n);
    };
    cast(x,    xb,   BT * NX);
    cast(W_h,  whb,  NR * NX);
    cast(W_h2, wh2b, NR * NR);
    cast(W_y,  wyb,  NX * NR);
    cast(G,    gbm,            NB * NB);   // rows 0..2047 of stacked weight
    cast(Bm,   gbm + (size_t)NB * NB, NB * NB);   // rows 2048..4095
    cast(W_p,  wpb,  NB * NB);
    cast(W_q,  wqb,  NB * NB);

    // h1 = relu(x @ W_h^T + b_h)            [8192,1024,K=4096]
    gemm_bt<1, 0, 1><<<dim3(NR / 128, BT / 128), blk, 0, stream>>>(
        xb, NX, whb, NX, b_h, nullptr, 0, h1, NR, BT, NR, NX);
    // h2 = relu(h1 @ W_h2^T + b_h2)         [8192,1024,K=1024]
    gemm_bt<1, 0, 1><<<dim3(NR / 128, BT / 128), blk, 0, stream>>>(
        h1, NR, wh2b, NR, b_h2, nullptr, 0, h2, NR, BT, NR, NR);

    // uw = h2 @ W_y^T + b_y                 [8192,4096,K=1024] -> fp32 d_out + bf16 ws
    gemm256<0, 1, 1><<<dim3(NX / 256, BT / 256), dim3(512), 0, stream>>>(
        h2, NR, wyb, NR, b_y, out, NX, uwb, NX, NR);
    // GBu = u @ [G;Bm]^T  via NEW deep-pipelined gemm256   [8192,4096,K=2048]
    gemm256<0, 0, 1><<<dim3(NX / 256, BT / 256), dim3(512), 0, stream>>>(
        uwb,      NX, gbm, NB, nullptr, nullptr, 0, GBu, NX, NB);
    // GBw = w @ [G;Bm]^T  via gemm_bt (same shape: within-run A/B reference)
    gemm_bt<0, 0, 1><<<dim3(NX / 128, BT / 128), blk, 0, stream>>>(
        uwb + NB, NX, gbm, NB, nullptr, nullptr, 0, GBw, NX, BT, NX, NB);
    // elementwise combine -> p_pre, q_pre (bf16)
    combine_pq<<<dim3(BT * NB / 4 / 256), blk, 0, stream>>>(
        uwb, GBu, GBw, bias_p, bias_q, pp, qp);
    // p = p_pre @ W_p^T + b_p -> d_out[33554432..]
    gemm256<0, 1, 0><<<dim3(NB / 256, BT / 256), dim3(512), 0, stream>>>(
        pp, NB, wpb, NB, b_p, out + (size_t)BT * NX, NB, nullptr, 0, NB);
    // q = q_pre @ W_q^T + b_q -> d_out[50331648..]
    gemm256<0, 1, 0><<<dim3(NB / 256, BT / 256), dim3(512), 0, stream>>>(
        qp, NB, wqb, NB, b_q, out + (size_t)BT * NX + (size_t)BT * NB, NB, nullptr, 0, NB);
}